// Round 1
// baseline (257.963 us; speedup 1.0000x reference)
//
#include <hip/hip_runtime.h>
#include <hip/hip_bf16.h>
#include <math.h>

#define NPTS 2048
#define BN   16384   // B*N
#define KNN_K 32

// ---------------- Kernel A: exact kNN (stable argsort semantics) ----------------
// One wave (64 lanes) per query. Points of the batch staged in LDS.
// Each lane owns 32 candidates (j = t*64 + lane) in registers.
// 32 extraction rounds; winner chosen by u64 min over (float_bits(dist)<<32 | j)
// == lexicographic (dist, index) == stable argsort tie-break.
__global__ __launch_bounds__(256) void knn_kernel(const float* __restrict__ pts,
                                                  int* __restrict__ knn) {
    __shared__ float px[NPTS], py[NPTS], pz[NPTS];
    const int b = blockIdx.x >> 9;              // 512 blocks per batch
    const int qbase = (blockIdx.x & 511) << 2;  // 4 queries per block
    const float* pb = pts + (size_t)b * NPTS * 3;
    for (int i = threadIdx.x; i < NPTS; i += 256) {
        px[i] = pb[i * 3 + 0];
        py[i] = pb[i * 3 + 1];
        pz[i] = pb[i * 3 + 2];
    }
    __syncthreads();
    const int wave = threadIdx.x >> 6;
    const int lane = threadIdx.x & 63;
    const int q = qbase + wave;
    const float qx = px[q], qy = py[q], qz = pz[q];

    // distances, exact f32 semantics (no FMA contraction), correctly-rounded sqrt
    float d[32];
#pragma unroll
    for (int t = 0; t < 32; ++t) {
        int j = t * 64 + lane;
        float dx = __fsub_rn(qx, px[j]);
        float dy = __fsub_rn(qy, py[j]);
        float dz = __fsub_rn(qz, pz[j]);
        float d2 = __fadd_rn(__fadd_rn(__fmul_rn(dx, dx), __fmul_rn(dy, dy)),
                             __fmul_rn(dz, dz));
        d[t] = __fsqrt_rn(d2);
    }

    unsigned fmask = 0xFFFFFFFFu;
    float gm[4]; int gmt[4];
#pragma unroll
    for (int g = 0; g < 4; ++g) {
        float mm = INFINITY; int tt = g * 8;
#pragma unroll
        for (int u = 0; u < 8; ++u) {
            int t = g * 8 + u;
            if (d[t] < mm) { mm = d[t]; tt = t; }   // strict < keeps lowest t on tie
        }
        gm[g] = mm; gmt[g] = tt;
    }

    int* kout = knn + ((size_t)b * NPTS + q) * KNN_K;
    for (int round = 0; round < KNN_K; ++round) {
        float m = gm[0]; int mt = gmt[0];
#pragma unroll
        for (int g = 1; g < 4; ++g)
            if (gm[g] < m) { m = gm[g]; mt = gmt[g]; }
        unsigned long long key =
            ((unsigned long long)__float_as_uint(m) << 32) |
            (unsigned)(mt * 64 + lane);
#pragma unroll
        for (int s = 1; s < 64; s <<= 1) {
            unsigned long long o = __shfl_xor(key, s, 64);
            key = (o < key) ? o : key;
        }
        unsigned jstar = (unsigned)key;     // winning candidate index in [0,2048)
        int wlane = jstar & 63;
        int wt = (int)(jstar >> 6);
        if (lane == wlane) fmask &= ~(1u << wt);
        int wg = __builtin_amdgcn_readfirstlane(wt >> 3);  // wave-uniform group
#pragma unroll
        for (int g = 0; g < 4; ++g) {
            if (g == wg) {   // scalar branch: only winner group recomputed
                float mm = INFINITY; int tt = g * 8;
#pragma unroll
                for (int u = 0; u < 8; ++u) {
                    int t = g * 8 + u;
                    float dd = (fmask & (1u << t)) ? d[t] : INFINITY;
                    if (dd < mm) { mm = dd; tt = t; }
                }
                gm[g] = mm; gmt[g] = tt;
            }
        }
        if (lane == 0) kout[round] = (int)jstar;
    }
}

// ---------------- Kernel B: layers 1+2 per point -> h2 [BN][128] ----------------
// thread = (point, 32-channel chunk of h2); chunk is wave-uniform -> scalar W loads
__global__ __launch_bounds__(256) void mlp12_kernel(const float* __restrict__ pts,
        const float* __restrict__ W1, const float* __restrict__ b1,
        const float* __restrict__ W2, const float* __restrict__ b2,
        float* __restrict__ h2out) {
    int gid = blockIdx.x * 256 + threadIdx.x;   // 65536 threads
    int p = gid & (BN - 1);
    int chunk = __builtin_amdgcn_readfirstlane(gid >> 14);  // 0..3, wave-uniform
    float x = pts[p * 3 + 0], y = pts[p * 3 + 1], z = pts[p * 3 + 2];
    float h1[64];
#pragma unroll
    for (int di = 0; di < 64; ++di) {
        float a = x * W1[di] + y * W1[64 + di] + z * W1[128 + di] + b1[di];
        h1[di] = fmaxf(a, 0.f);
    }
    float acc[32];
#pragma unroll
    for (int j = 0; j < 32; ++j) acc[j] = 0.f;
    const float* w2 = W2 + chunk * 32;
    for (int di = 0; di < 64; ++di) {
        float h = h1[di];
#pragma unroll
        for (int j = 0; j < 32; ++j) acc[j] += h * w2[di * 128 + j];
    }
    float* o = h2out + (size_t)p * 128 + chunk * 32;
    const float* bb = b2 + chunk * 32;
#pragma unroll
    for (int j = 0; j < 32; ++j) o[j] = fmaxf(acc[j] + bb[j], 0.f);
}

// ---------------- Kernel C: layer 3 -> f3 [BN][256] ----------------
// thread = (4 points, 8-channel chunk); register-blocked to amortize W3 traffic
__global__ __launch_bounds__(256) void mlp3_kernel(const float* __restrict__ h2g,
        const float* __restrict__ W3, const float* __restrict__ b3,
        float* __restrict__ f3) {
    int gid = blockIdx.x * 256 + threadIdx.x;   // 131072 threads
    int chunk = gid & 31;
    int pg = gid >> 5;                          // 4096 point-groups of 4
    int c0 = chunk * 8;
    float acc[4][8];
#pragma unroll
    for (int pt = 0; pt < 4; ++pt)
#pragma unroll
        for (int j = 0; j < 8; ++j) acc[pt][j] = 0.f;
    const float* hbase = h2g + (size_t)pg * 4 * 128;
    for (int c = 0; c < 128; ++c) {
        float w[8];
#pragma unroll
        for (int j = 0; j < 8; ++j) w[j] = W3[c * 256 + c0 + j];
#pragma unroll
        for (int pt = 0; pt < 4; ++pt) {
            float h = hbase[pt * 128 + c];
#pragma unroll
            for (int j = 0; j < 8; ++j) acc[pt][j] += h * w[j];
        }
    }
#pragma unroll
    for (int pt = 0; pt < 4; ++pt) {
        float* o = f3 + ((size_t)(pg * 4 + pt)) * 256 + c0;
#pragma unroll
        for (int j = 0; j < 8; ++j) o[j] = fmaxf(acc[pt][j] + b3[c0 + j], 0.f);
    }
}

// ---------------- Kernel D: gather + mean over 32 neighbors ----------------
__global__ __launch_bounds__(256) void gather_mean_kernel(const float* __restrict__ f3,
        const int* __restrict__ knn, float* __restrict__ out) {
    int q = blockIdx.x;          // 0..16383 (global query = b*2048+n)
    int b = q >> 11;
    int c = threadIdx.x;         // 0..255 output channel
    const int* kq = knn + (size_t)q * KNN_K;
    float acc = 0.f;
#pragma unroll
    for (int k = 0; k < KNN_K; ++k) {
        int j = kq[k];           // local index within batch
        acc += f3[((size_t)b * NPTS + j) * 256 + c];
    }
    out[(size_t)q * 256 + c] = acc * 0.03125f;   // exact /32
}

extern "C" void kernel_launch(void* const* d_in, const int* in_sizes, int n_in,
                              void* d_out, int out_size, void* d_ws, size_t ws_size,
                              hipStream_t stream) {
    const float* pts = (const float*)d_in[0];
    const float* W1  = (const float*)d_in[1];
    const float* b1  = (const float*)d_in[2];
    const float* W2  = (const float*)d_in[3];
    const float* b2  = (const float*)d_in[4];
    const float* W3  = (const float*)d_in[5];
    const float* b3  = (const float*)d_in[6];
    float* out = (float*)d_out;
    char* ws = (char*)d_ws;
    int*   knn = (int*)ws;                               // 2 MB
    float* h2g = (float*)(ws + ((size_t)2 << 20));       // 8 MB
    float* f3  = (float*)(ws + ((size_t)10 << 20));      // 16.8 MB

    hipLaunchKernelGGL(knn_kernel,        dim3(4096),  dim3(256), 0, stream, pts, knn);
    hipLaunchKernelGGL(mlp12_kernel,      dim3(256),   dim3(256), 0, stream, pts, W1, b1, W2, b2, h2g);
    hipLaunchKernelGGL(mlp3_kernel,       dim3(512),   dim3(256), 0, stream, h2g, W3, b3, f3);
    hipLaunchKernelGGL(gather_mean_kernel,dim3(16384), dim3(256), 0, stream, f3, knn, out);
}

// Round 3
// 207.832 us; speedup vs baseline: 1.2412x; 1.2412x over previous
//
#include <hip/hip_runtime.h>
#include <hip/hip_bf16.h>
#include <math.h>

#define NPTS 2048
#define BN   16384
#define KNN_K 32
typedef unsigned long long u64;
#define INF64 0xFFFFFFFFFFFFFFFFull

__device__ __forceinline__ u64 umin64(u64 a, u64 b) { return a < b ? a : b; }

// ---------------- Kernel A: exact kNN via prune + bitonic sort ----------------
// One wave per query. T_pre = 32nd-smallest lane-min bounds the 32nd-smallest
// element from above -> survivor set {d <= T_pre} (exp ~44) contains answer.
// Compact survivors to LDS, one 64-lane bitonic sort on u64 (dist,idx) keys.
__global__ __launch_bounds__(256) void knn_kernel(const float* __restrict__ pts,
                                                  int* __restrict__ knn) {
    __shared__ float px[NPTS], py[NPTS], pz[NPTS];
    __shared__ u64 surv[4][128];
    const int b = blockIdx.x >> 9;
    const int qbase = (blockIdx.x & 511) << 2;
    const float* pb = pts + (size_t)b * NPTS * 3;
    for (int i = threadIdx.x; i < NPTS; i += 256) {
        px[i] = pb[i * 3 + 0];
        py[i] = pb[i * 3 + 1];
        pz[i] = pb[i * 3 + 2];
    }
    __syncthreads();
    const int wave = threadIdx.x >> 6, lane = threadIdx.x & 63;
    const int q = qbase + wave;
    const float qx = px[q], qy = py[q], qz = pz[q];

    // exact reference-order distances (no FMA contraction, correctly-rounded sqrt)
    float d[32];
#pragma unroll
    for (int t = 0; t < 32; ++t) {
        int j = t * 64 + lane;
        float dx = __fsub_rn(qx, px[j]);
        float dy = __fsub_rn(qy, py[j]);
        float dz = __fsub_rn(qz, pz[j]);
        float d2 = __fadd_rn(__fadd_rn(__fmul_rn(dx, dx), __fmul_rn(dy, dy)),
                             __fmul_rn(dz, dz));
        d[t] = __fsqrt_rn(d2);
    }

    // per-lane min dist
    float lmin = d[0];
#pragma unroll
    for (int t = 1; t < 32; ++t) lmin = fminf(lmin, d[t]);

    // bitonic sort of 64 lane-minima (ascending across lanes)
    float v = lmin;
#pragma unroll
    for (int k = 2; k <= 64; k <<= 1) {
#pragma unroll
        for (int j = k >> 1; j > 0; j >>= 1) {
            float o = __shfl_xor(v, j, 64);
            bool up = ((lane & k) == 0);
            bool low = ((lane & j) == 0);
            float mn = fminf(v, o), mx = fmaxf(v, o);
            v = (low == up) ? mn : mx;
        }
    }
    float Tpre = __shfl(v, 31, 64);   // 32nd smallest lane-min (upper bound)

    // ballot-compact survivors {d <= Tpre} into per-wave LDS as u64 keys
    u64* sw = surv[wave];
    unsigned cnt = 0;
#pragma unroll
    for (int t = 0; t < 32; ++t) {
        bool sel = (d[t] <= Tpre);
        u64 m = __ballot(sel);
        if (sel) {
            u64 key = ((u64)__float_as_uint(d[t]) << 32) | (unsigned)(t * 64 + lane);
            unsigned pos = cnt + (unsigned)__popcll(m & ((1ull << lane) - 1ull));
            if (pos < 128) sw[pos] = key;
        }
        cnt += (unsigned)__popcll(m);
    }

    int* kout = knn + ((size_t)b * NPTS + q) * KNN_K;
    __asm__ volatile("s_waitcnt lgkmcnt(0)" ::: "memory");  // own-wave LDS W->R fence

    if (cnt <= 64) {
        u64 key = (lane < (int)cnt) ? sw[lane] : INF64;
#pragma unroll
        for (int k = 2; k <= 64; k <<= 1) {
#pragma unroll
            for (int j = k >> 1; j > 0; j >>= 1) {
                u64 o = __shfl_xor(key, j, 64);
                bool up = ((lane & k) == 0);
                bool low = ((lane & j) == 0);
                bool lt = key < o;
                u64 mn = lt ? key : o, mx = lt ? o : key;
                key = (low == up) ? mn : mx;
            }
        }
        if (lane < KNN_K) kout[lane] = (int)(unsigned)(key & 0xFFFFFFFFull);
    } else {
        // rare exact fallback (survivors > 64): full 32-round extraction
        unsigned fmask = 0xFFFFFFFFu;
        for (int r = 0; r < KNN_K; ++r) {
            u64 mm = INF64;
#pragma unroll
            for (int t = 0; t < 32; ++t) {
                u64 kk = ((u64)__float_as_uint(d[t]) << 32) | (unsigned)(t * 64 + lane);
                mm = umin64(mm, ((fmask >> t) & 1u) ? kk : INF64);
            }
#pragma unroll
            for (int s = 1; s < 64; s <<= 1) mm = umin64(mm, __shfl_xor(mm, s, 64));
            unsigned j = (unsigned)(mm & 0xFFFFFFFFull);
            if (lane == (int)(j & 63)) fmask &= ~(1u << (j >> 6));
            if (lane == 0) kout[r] = (int)j;
        }
    }
}

// ---------------- Kernel B: layers 1+2 -> h2 [BN][128] ----------------
// thread = (point, 16-channel chunk); 131072 threads (2 waves/SIMD)
__global__ __launch_bounds__(256) void mlp12_kernel(const float* __restrict__ pts,
        const float* __restrict__ W1, const float* __restrict__ b1,
        const float* __restrict__ W2, const float* __restrict__ b2,
        float* __restrict__ h2out) {
    int gid = blockIdx.x * 256 + threadIdx.x;
    int p = gid & (BN - 1);
    int chunk = __builtin_amdgcn_readfirstlane(gid >> 14);  // 0..7, wave-uniform
    float x = pts[p * 3 + 0], y = pts[p * 3 + 1], z = pts[p * 3 + 2];
    float h1[64];
#pragma unroll
    for (int i = 0; i < 64; ++i) {
        float a = x * W1[i] + y * W1[64 + i] + z * W1[128 + i] + b1[i];
        h1[i] = fmaxf(a, 0.f);
    }
    float acc[16];
#pragma unroll
    for (int j = 0; j < 16; ++j) acc[j] = 0.f;
    const float* w2 = W2 + chunk * 16;
    for (int i = 0; i < 64; ++i) {
        float h = h1[i];
#pragma unroll
        for (int j = 0; j < 16; ++j) acc[j] += h * w2[i * 128 + j];
    }
    float* o = h2out + (size_t)p * 128 + chunk * 16;
    const float* bb = b2 + chunk * 16;
#pragma unroll
    for (int j = 0; j < 16; ++j) o[j] = fmaxf(acc[j] + bb[j], 0.f);
}

// ---------------- Kernel C: layer 3 -> f3 [BN][256], float4 loads ----------------
__global__ __launch_bounds__(256) void mlp3_kernel(const float* __restrict__ h2g,
        const float* __restrict__ W3, const float* __restrict__ b3,
        float* __restrict__ f3) {
    int gid = blockIdx.x * 256 + threadIdx.x;   // 131072
    int chunk = gid & 31;
    int pg = gid >> 5;
    int c0 = chunk * 8;
    float4 a0[4], a1[4];
#pragma unroll
    for (int pt = 0; pt < 4; ++pt) {
        a0[pt] = make_float4(0.f, 0.f, 0.f, 0.f);
        a1[pt] = make_float4(0.f, 0.f, 0.f, 0.f);
    }
    const float* hbase = h2g + (size_t)pg * 4 * 128;
    for (int c4 = 0; c4 < 32; ++c4) {
        float4 hv[4];
#pragma unroll
        for (int pt = 0; pt < 4; ++pt)
            hv[pt] = *(const float4*)(hbase + pt * 128 + c4 * 4);
#pragma unroll
        for (int u = 0; u < 4; ++u) {
            const float* wr = W3 + (size_t)(c4 * 4 + u) * 256 + c0;
            float4 w0 = *(const float4*)wr;
            float4 w1 = *(const float4*)(wr + 4);
#pragma unroll
            for (int pt = 0; pt < 4; ++pt) {
                float h = (u == 0) ? hv[pt].x : (u == 1) ? hv[pt].y
                          : (u == 2) ? hv[pt].z : hv[pt].w;
                a0[pt].x += h * w0.x; a0[pt].y += h * w0.y;
                a0[pt].z += h * w0.z; a0[pt].w += h * w0.w;
                a1[pt].x += h * w1.x; a1[pt].y += h * w1.y;
                a1[pt].z += h * w1.z; a1[pt].w += h * w1.w;
            }
        }
    }
    float4 bl = *(const float4*)(b3 + c0);
    float4 bh = *(const float4*)(b3 + c0 + 4);
#pragma unroll
    for (int pt = 0; pt < 4; ++pt) {
        float* o = f3 + ((size_t)(pg * 4 + pt)) * 256 + c0;
        float4 r0 = make_float4(fmaxf(a0[pt].x + bl.x, 0.f), fmaxf(a0[pt].y + bl.y, 0.f),
                                fmaxf(a0[pt].z + bl.z, 0.f), fmaxf(a0[pt].w + bl.w, 0.f));
        float4 r1 = make_float4(fmaxf(a1[pt].x + bh.x, 0.f), fmaxf(a1[pt].y + bh.y, 0.f),
                                fmaxf(a1[pt].z + bh.z, 0.f), fmaxf(a1[pt].w + bh.w, 0.f));
        *(float4*)o = r0;
        *(float4*)(o + 4) = r1;
    }
}

// ---------------- Kernel D: gather + mean, float4 (wave reads full row) ----------------
__global__ __launch_bounds__(256) void gather_mean_kernel(const float* __restrict__ f3,
        const int* __restrict__ knn, float* __restrict__ out) {
    int wave = threadIdx.x >> 6, lane = threadIdx.x & 63;
    int q = blockIdx.x * 4 + wave;     // 4096 blocks
    int b = q >> 11;
    const int* kq = knn + (size_t)q * KNN_K;
    const float4* fb = (const float4*)(f3 + (size_t)b * NPTS * 256);
    float4 acc = make_float4(0.f, 0.f, 0.f, 0.f);
#pragma unroll
    for (int k = 0; k < KNN_K; ++k) {
        int j = kq[k];
        float4 v2 = fb[(size_t)j * 64 + lane];
        acc.x += v2.x; acc.y += v2.y; acc.z += v2.z; acc.w += v2.w;
    }
    float4 r = make_float4(acc.x * 0.03125f, acc.y * 0.03125f,
                           acc.z * 0.03125f, acc.w * 0.03125f);
    *(float4*)(out + (size_t)q * 256 + lane * 4) = r;
}

extern "C" void kernel_launch(void* const* d_in, const int* in_sizes, int n_in,
                              void* d_out, int out_size, void* d_ws, size_t ws_size,
                              hipStream_t stream) {
    const float* pts = (const float*)d_in[0];
    const float* W1  = (const float*)d_in[1];
    const float* b1  = (const float*)d_in[2];
    const float* W2  = (const float*)d_in[3];
    const float* b2  = (const float*)d_in[4];
    const float* W3  = (const float*)d_in[5];
    const float* b3  = (const float*)d_in[6];
    float* out = (float*)d_out;
    char* ws = (char*)d_ws;
    int*   knn = (int*)ws;                               // 2 MB
    float* h2g = (float*)(ws + ((size_t)2 << 20));       // 8 MB
    float* f3  = (float*)(ws + ((size_t)10 << 20));      // 16.8 MB

    hipLaunchKernelGGL(knn_kernel,         dim3(4096), dim3(256), 0, stream, pts, knn);
    hipLaunchKernelGGL(mlp12_kernel,       dim3(512),  dim3(256), 0, stream, pts, W1, b1, W2, b2, h2g);
    hipLaunchKernelGGL(mlp3_kernel,        dim3(512),  dim3(256), 0, stream, h2g, W3, b3, f3);
    hipLaunchKernelGGL(gather_mean_kernel, dim3(4096), dim3(256), 0, stream, f3, knn, out);
}